// Round 4
// baseline (126.947 us; speedup 1.0000x reference)
//
#include <hip/hip_runtime.h>
#include <math.h>

// Problem constants (fixed by setup_inputs)
#define N_TOTAL 2097152
#define NT 1024             // threads per block (16 waves -> 4 waves/SIMD)
#define NC 8                // elements per thread
#define EPB (NT * NC)       // 8192 elements per block
#define NB (N_TOTAL / EPB)  // 256 blocks == #CUs -> co-residency guaranteed
#define NWAVE (NT / 64)     // 16 waves per block

// Projective map on homogeneous (x, g, 1):
//   x' = (al*x + be) / (ga*x + de)
//   g' = (e*x + c*g + f) / (ga*x + de)
// Matrix [[al,0,be],[e,c,f],[ga,0,de]] — closed under composition.
// Compose algebra in DOUBLE; per-element decay P in fp32 (matches the fp32
// reference: fp32 diff of adjacent sorted t is exact, expf ~1 ulp).
struct DMat { double al, be, ga, de, c, e, f; };

__device__ __forceinline__ DMat dmat_identity() {
    DMat m; m.al = 1.0; m.be = 0.0; m.ga = 0.0; m.de = 1.0; m.c = 1.0; m.e = 0.0; m.f = 0.0;
    return m;
}

// A applied AFTER B (matrix product A*B)
__device__ __forceinline__ DMat dmat_compose(const DMat& A, const DMat& B) {
    DMat r;
    r.al = A.al * B.al + A.be * B.ga;
    r.be = A.al * B.be + A.be * B.de;
    r.ga = A.ga * B.al + A.de * B.ga;
    r.de = A.ga * B.be + A.de * B.de;
    r.c  = A.c * B.c;
    r.e  = A.e * B.al + A.c * B.e + A.f * B.ga;
    r.f  = A.e * B.be + A.c * B.f + A.f * B.de;
    return r;
}

// Scale-invariant normalization; guarded so it can never manufacture NaN/Inf.
// Inputs to every unnormalized scan segment are normalized (max entry <= 1),
// so intermediate growth over <=6 unnormalized rounds is bounded well inside
// fp64 range; we only normalize at segment boundaries.
__device__ __forceinline__ void dmat_normalize(DMat& m) {
    double mx = fmax(fabs(m.al), fabs(m.be));
    mx = fmax(mx, fabs(m.ga));
    mx = fmax(mx, fabs(m.de));
    mx = fmax(mx, fabs(m.c));
    mx = fmax(mx, fabs(m.e));
    mx = fmax(mx, fabs(m.f));
    if (!(mx > 0.0) || isinf(mx)) return;   // all-zero or corrupt: leave as-is
    double inv = 1.0 / mx;
    m.al *= inv; m.be *= inv; m.ga *= inv; m.de *= inv;
    m.c *= inv; m.e *= inv; m.f *= inv;
}

__device__ __forceinline__ DMat dmat_shfl_up(const DMat& m, int d) {
    DMat r;
    r.al = __shfl_up(m.al, d); r.be = __shfl_up(m.be, d);
    r.ga = __shfl_up(m.ga, d); r.de = __shfl_up(m.de, d);
    r.c  = __shfl_up(m.c,  d); r.e  = __shfl_up(m.e,  d);
    r.f  = __shfl_up(m.f,  d);
    return r;
}

__device__ __forceinline__ DMat dmat_shfl_bcast(const DMat& m, int src) {
    DMat r;
    r.al = __shfl(m.al, src); r.be = __shfl(m.be, src);
    r.ga = __shfl(m.ga, src); r.de = __shfl(m.de, src);
    r.c  = __shfl(m.c,  src); r.e  = __shfl(m.e,  src);
    r.f  = __shfl(m.f,  src);
    return r;
}

// Barrier-free inclusive scan across the 64 lanes of a wave.
__device__ __forceinline__ DMat dmat_wave_scan64(DMat mine, int lane) {
    #pragma unroll
    for (int d = 1; d < 64; d <<= 1) {
        DMat o = dmat_shfl_up(mine, d);
        if (lane >= d) mine = dmat_compose(mine, o);
    }
    return mine;
}

__device__ __forceinline__ DMat elem_mat(double P, double a, double U, double V, double yy) {
    double p = P * P;
    DMat m;
    m.al = p * (a - 2.0 * U * V);
    m.be = V * V;
    m.ga = -(p * U * U);
    m.de = a;
    m.c  = P * (a - U * V);
    m.e  = -(yy * p * U);
    m.f  = yy * V;
    return m;
}

// Register-resident 4-way select (avoid runtime-indexed array -> scratch).
__device__ __forceinline__ double band_amp(int b, double a1, double a2, double a3) {
    double lo = (b & 1) ? a1 : 1.0;
    double hi = (b & 1) ? a3 : a2;
    return (b & 2) ? hi : lo;
}

// Device-coherent (agent-scope) matrix store/load for cross-block handoff.
__device__ __forceinline__ void dmat_store_agent(double* p, const DMat& m) {
    __hip_atomic_store(&p[0], m.al, __ATOMIC_RELAXED, __HIP_MEMORY_SCOPE_AGENT);
    __hip_atomic_store(&p[1], m.be, __ATOMIC_RELAXED, __HIP_MEMORY_SCOPE_AGENT);
    __hip_atomic_store(&p[2], m.ga, __ATOMIC_RELAXED, __HIP_MEMORY_SCOPE_AGENT);
    __hip_atomic_store(&p[3], m.de, __ATOMIC_RELAXED, __HIP_MEMORY_SCOPE_AGENT);
    __hip_atomic_store(&p[4], m.c,  __ATOMIC_RELAXED, __HIP_MEMORY_SCOPE_AGENT);
    __hip_atomic_store(&p[5], m.e,  __ATOMIC_RELAXED, __HIP_MEMORY_SCOPE_AGENT);
    __hip_atomic_store(&p[6], m.f,  __ATOMIC_RELAXED, __HIP_MEMORY_SCOPE_AGENT);
}

__device__ __forceinline__ DMat dmat_load_agent(const double* p) {
    DMat m;
    m.al = __hip_atomic_load(&p[0], __ATOMIC_RELAXED, __HIP_MEMORY_SCOPE_AGENT);
    m.be = __hip_atomic_load(&p[1], __ATOMIC_RELAXED, __HIP_MEMORY_SCOPE_AGENT);
    m.ga = __hip_atomic_load(&p[2], __ATOMIC_RELAXED, __HIP_MEMORY_SCOPE_AGENT);
    m.de = __hip_atomic_load(&p[3], __ATOMIC_RELAXED, __HIP_MEMORY_SCOPE_AGENT);
    m.c  = __hip_atomic_load(&p[4], __ATOMIC_RELAXED, __HIP_MEMORY_SCOPE_AGENT);
    m.e  = __hip_atomic_load(&p[5], __ATOMIC_RELAXED, __HIP_MEMORY_SCOPE_AGENT);
    m.f  = __hip_atomic_load(&p[6], __ATOMIC_RELAXED, __HIP_MEMORY_SCOPE_AGENT);
    return m;
}

// ------------------------- single fused kernel ---------------------------
// phase 1: per-thread chain (replay data register-resident, 25 VGPR) +
//          shuffle wave scan + one LDS step for the 16 wave totals
// grid barrier (256 blocks = 1 block/CU -> always co-resident)
// phase 2: redundant spine shuffle-scan of 256 block composites
// phase 3: replay from registers, reduce, done-counter finalize
__global__ __launch_bounds__(NT, 4) void k_fused(     // 4 waves/EU -> 128 VGPR cap
    const float* __restrict__ t, const int* __restrict__ band,
    const float* __restrict__ y, const float* __restrict__ yerr,
    const float* __restrict__ lad, const float* __restrict__ lkp,
    double* __restrict__ L, double* __restrict__ accum,
    unsigned int* __restrict__ bar0, unsigned int* __restrict__ done,
    float* __restrict__ out)
{
    __shared__ double totW[7 * 16];   // 16 wave totals
    __shared__ double spI[7 * NB];    // 256 spine inclusive values
    __shared__ double spT[7 * 4];     // 4 spine wave totals
    __shared__ double red[2 * NWAVE];

    const int tid  = threadIdx.x;
    const int lane = tid & 63;
    const int wid  = tid >> 6;
    const int bid  = blockIdx.x;

    const double sigma2 = exp(2.0 * (double)lkp[0]);
    const float inv_ell_f = expf(-lkp[1]);
    const double amp1 = exp((double)lad[0]);
    const double amp2 = exp((double)lad[1]);
    const double amp3 = exp((double)lad[2]);

    const int gid  = bid * NT + tid;
    const int base = gid * NC;
    const bool first = (gid == 0);

    // ---- loads (all issued up front) ----
    float4 tvA = *reinterpret_cast<const float4*>(t + base);
    float4 tvB = *reinterpret_cast<const float4*>(t + base + 4);
    float4 yvA = *reinterpret_cast<const float4*>(y + base);
    float4 yvB = *reinterpret_cast<const float4*>(y + base + 4);
    float4 evA = *reinterpret_cast<const float4*>(yerr + base);
    float4 evB = *reinterpret_cast<const float4*>(yerr + base + 4);
    int4   bvA = *reinterpret_cast<const int4*>(band + base);
    int4   bvB = *reinterpret_cast<const int4*>(band + base + 4);
    float tpA = first ? 0.0f : t[base - 1];
    float tpB = tvA.w;                       // t[base+3], already loaded

    float tA[4] = {tvA.x, tvA.y, tvA.z, tvA.w};
    float yA[4] = {yvA.x, yvA.y, yvA.z, yvA.w};
    float eA[4] = {evA.x, evA.y, evA.z, evA.w};
    int   bA[4] = {bvA.x, bvA.y, bvA.z, bvA.w};
    float tB[4] = {tvB.x, tvB.y, tvB.z, tvB.w};
    float yB[4] = {yvB.x, yvB.y, yvB.z, yvB.w};
    float eB[4] = {evB.x, evB.y, evB.z, evB.w};
    int   bB[4] = {bvB.x, bvB.y, bvB.z, bvB.w};

    // replay state: 3x8 fp32 + 1 packed-band u32 = 25 VGPRs (was 40)
    float Pv[NC], av[NC], yvv[NC];
    unsigned int bpack = 0;

    // ---- phase 1: two independent 4-element chains (2x ILP) ----
    DMat accA = dmat_identity();
    DMat accB = dmat_identity();
    #pragma unroll
    for (int j = 0; j < 4; ++j) {
        {   // chain A: elements [0, 4)
            int b = bA[j] & 3;
            bpack |= (unsigned int)b << (2 * j);
            double u = band_amp(b, amp1, amp2, amp3);
            double U = sigma2 * u;
            double a = (double)eA[j] * (double)eA[j] + U * u;
            float dt = tA[j] - tpA; tpA = tA[j];
            float pf = (first && j == 0) ? 0.0f : expf(-dt * inv_ell_f);
            Pv[j] = pf; av[j] = (float)a; yvv[j] = yA[j];
            accA = dmat_compose(elem_mat((double)pf, a, U, u, (double)yA[j]), accA);
        }
        {   // chain B: elements [4, 8) — independent of chain A
            int b = bB[j] & 3;
            bpack |= (unsigned int)b << (2 * (4 + j));
            double u = band_amp(b, amp1, amp2, amp3);
            double U = sigma2 * u;
            double a = (double)eB[j] * (double)eB[j] + U * u;
            float dt = tB[j] - tpB; tpB = tB[j];
            float pf = expf(-dt * inv_ell_f);
            Pv[4 + j] = pf; av[4 + j] = (float)a; yvv[4 + j] = yB[j];
            accB = dmat_compose(elem_mat((double)pf, a, U, u, (double)yB[j]), accB);
        }
    }
    DMat acc = dmat_compose(accB, accA);
    dmat_normalize(acc);

    // ---- barrier-free wave scan; 1 LDS step for the 16 wave totals ----
    DMat incl = dmat_wave_scan64(acc, lane);
    dmat_normalize(incl);
    DMat laneExcl = dmat_shfl_up(incl, 1);   // lane 0: garbage (handled below)
    if (lane == 63) {                        // publish wave total
        totW[0 * 16 + wid] = incl.al; totW[1 * 16 + wid] = incl.be;
        totW[2 * 16 + wid] = incl.ga; totW[3 * 16 + wid] = incl.de;
        totW[4 * 16 + wid] = incl.c;  totW[5 * 16 + wid] = incl.e;
        totW[6 * 16 + wid] = incl.f;
    }
    __syncthreads();

    // redundant 16-element shuffle scan of wave totals (every wave; no barrier)
    DMat tv = dmat_identity();
    if (lane < 16) {
        tv.al = totW[0 * 16 + lane]; tv.be = totW[1 * 16 + lane];
        tv.ga = totW[2 * 16 + lane]; tv.de = totW[3 * 16 + lane];
        tv.c  = totW[4 * 16 + lane]; tv.e  = totW[5 * 16 + lane];
        tv.f  = totW[6 * 16 + lane];
    }
    #pragma unroll
    for (int d = 1; d < 16; d <<= 1) {
        DMat o = dmat_shfl_up(tv, d);
        if (lane >= d && lane < 16) tv = dmat_compose(tv, o);
    }
    dmat_normalize(tv);

    // publish block-inclusive composite (scanned[15] lives in lane 15, wave 0)
    if (tid == 15) {
        dmat_store_agent(L + bid * 7, tv);
        __threadfence();                     // release: L visible device-wide
    }

    // wave-exclusive prefix within block; thread-exclusive within block
    DMat Et;
    if (wid == 0) {
        Et = (lane == 0) ? dmat_identity() : laneExcl;
    } else {
        DMat waveExcl = dmat_shfl_bcast(tv, wid - 1);
        Et = (lane == 0) ? waveExcl : dmat_compose(laneExcl, waveExcl);
    }

    // ---- grid barrier ----
    __syncthreads();
    if (tid == 0) {
        __threadfence();
        atomicAdd(bar0, 1u);
        while (__hip_atomic_load(bar0, __ATOMIC_ACQUIRE,
                                 __HIP_MEMORY_SCOPE_AGENT) < NB) {
            __builtin_amdgcn_s_sleep(2);
        }
    }
    __syncthreads();

    // ---- phase 2: redundant spine scan (4 waves shuffle-scan 256 blocks) ----
    if (wid < 4) {
        DMat sv = dmat_load_agent(L + tid * 7);   // tid < 256 here
        sv = dmat_wave_scan64(sv, lane);
        dmat_normalize(sv);
        spI[0 * NB + tid] = sv.al; spI[1 * NB + tid] = sv.be;
        spI[2 * NB + tid] = sv.ga; spI[3 * NB + tid] = sv.de;
        spI[4 * NB + tid] = sv.c;  spI[5 * NB + tid] = sv.e;
        spI[6 * NB + tid] = sv.f;
        if (lane == 63) {
            spT[0 * 4 + wid] = sv.al; spT[1 * 4 + wid] = sv.be;
            spT[2 * 4 + wid] = sv.ga; spT[3 * 4 + wid] = sv.de;
            spT[4 * 4 + wid] = sv.c;  spT[5 * 4 + wid] = sv.e;
            spT[6 * 4 + wid] = sv.f;
        }
    }
    __syncthreads();

    // block-exclusive composite Eb (uniform; LDS broadcast reads)
    DMat Eb = dmat_identity();
    if (bid > 0) {
        const int i = bid - 1;
        Eb.al = spI[0 * NB + i]; Eb.be = spI[1 * NB + i];
        Eb.ga = spI[2 * NB + i]; Eb.de = spI[3 * NB + i];
        Eb.c  = spI[4 * NB + i]; Eb.e  = spI[5 * NB + i];
        Eb.f  = spI[6 * NB + i];
        const int nw = i >> 6;
        for (int w = nw - 1; w >= 0; --w) {
            DMat T;
            T.al = spT[0 * 4 + w]; T.be = spT[1 * 4 + w];
            T.ga = spT[2 * 4 + w]; T.de = spT[3 * 4 + w];
            T.c  = spT[4 * 4 + w]; T.e  = spT[5 * 4 + w];
            T.f  = spT[6 * 4 + w];
            Eb = dmat_compose(Eb, T);
        }
        dmat_normalize(Eb);
    }

    // full-history exclusive composite for this thread
    DMat F = dmat_compose(Et, Eb);
    dmat_normalize(F);
    // apply at (x,g) = (0,0); x=0 is far from the repelling fixed point (~1)
    double x = 0.0, g = 0.0;
    if (F.de != 0.0 && !isinf(F.de)) {
        double invde = 1.0 / F.de;
        x = F.be * invde;
        g = F.f  * invde;
    }
    if (!isfinite(x)) x = 0.0;
    if (!isfinite(g)) g = 0.0;

    // ---- phase 3: replay from registers (u,U,V recomputed from bpack) ----
    double s_logD = 0.0, s_quad = 0.0, pd = 1.0;
    #pragma unroll
    for (int k = 0; k < NC; ++k) {
        int b = (int)((bpack >> (2 * k)) & 3u);
        double V = band_amp(b, amp1, amp2, amp3);
        double U = sigma2 * V;
        double P = (double)Pv[k], a = (double)av[k], yy = (double)yvv[k];
        double p = P * P;
        double S = p * x;
        double D = a - U * U * S;
        if (!(D > 1e-300)) D = 1e-300;  // NaN-proof; never triggers if math is right
        double invD = 1.0 / D;
        double W = (V - S * U) * invD;
        double gn = P * g;
        double z = yy - U * gn;
        pd *= D;
        s_quad = fma(z * z, invD, s_quad);
        x = fma(D * W, W, S);
        g = fma(W, z, gn);
    }
    s_logD = log(pd);   // product of 8 D's stays in fp64 range comfortably

    // wave reduce, then cross-wave step
    #pragma unroll
    for (int off = 32; off > 0; off >>= 1) {
        s_logD += __shfl_down(s_logD, off);
        s_quad += __shfl_down(s_quad, off);
    }
    if (lane == 0) { red[wid] = s_logD; red[NWAVE + wid] = s_quad; }
    __syncthreads();
    if (tid == 0) {
        double l = 0.0, q = 0.0;
        #pragma unroll
        for (int w = 0; w < NWAVE; ++w) { l += red[w]; q += red[NWAVE + w]; }
        atomicAdd(&accum[0], l);
        atomicAdd(&accum[1], q);
        __threadfence();
        unsigned int old = atomicAdd(done, 1u);
        if (old == NB - 1) {   // last block: finalize (atomic RMW reads = coherent)
            double LL = atomicAdd(&accum[0], 0.0);
            double QQ = atomicAdd(&accum[1], 0.0);
            out[0] = (float)(-0.5 * (QQ + LL
                     + (double)N_TOTAL * 1.8378770664093454836));  // log(2*pi)
        }
    }
}

extern "C" void kernel_launch(void* const* d_in, const int* in_sizes, int n_in,
                              void* d_out, int out_size, void* d_ws, size_t ws_size,
                              hipStream_t stream)
{
    const float* t    = (const float*)d_in[0];
    const int*   band = (const int*)d_in[1];
    const float* y    = (const float*)d_in[2];
    const float* yerr = (const float*)d_in[3];
    const float* lad  = (const float*)d_in[4];
    const float* lkp  = (const float*)d_in[5];

    double* dws        = (double*)d_ws;
    double* accum      = dws;                         // 2 doubles
    unsigned int* ctrs = (unsigned int*)(dws + 2);    // bar0, done
    double* L          = dws + 4;                     // NB * 7 doubles (14 KB)

    // zero accum + control words (workspace is poisoned between iterations)
    hipMemsetAsync(dws, 0, 32, stream);
    k_fused<<<NB, NT, 0, stream>>>(t, band, y, yerr, lad, lkp,
                                   L, accum, ctrs, ctrs + 1, (float*)d_out);
}

// Round 5
// 122.364 us; speedup vs baseline: 1.0375x; 1.0375x over previous
//
#include <hip/hip_runtime.h>
#include <math.h>

// Problem constants (fixed by setup_inputs)
#define N_TOTAL 2097152
#define NT 512              // threads per block (8 waves)
#define NC 16               // elements per thread
#define EPB (NT * NC)       // 8192 elements per block
#define NB (N_TOTAL / EPB)  // 256 blocks == #CUs -> co-residency guaranteed
#define NWAVE (NT / 64)     // 8 waves per block

// Projective map on homogeneous (x, g, 1):
//   x' = (al*x + be) / (ga*x + de)
//   g' = (e*x + c*g + f) / (ga*x + de)
// Matrix [[al,0,be],[e,c,f],[ga,0,de]] — closed under composition.
// Compose algebra in DOUBLE; per-element decay P in fp32 (matches the fp32
// reference: fp32 diff of adjacent sorted t is exact, expf ~1 ulp).
struct DMat { double al, be, ga, de, c, e, f; };

__device__ __forceinline__ DMat dmat_identity() {
    DMat m; m.al = 1.0; m.be = 0.0; m.ga = 0.0; m.de = 1.0; m.c = 1.0; m.e = 0.0; m.f = 0.0;
    return m;
}

// A applied AFTER B (matrix product A*B)
__device__ __forceinline__ DMat dmat_compose(const DMat& A, const DMat& B) {
    DMat r;
    r.al = A.al * B.al + A.be * B.ga;
    r.be = A.al * B.be + A.be * B.de;
    r.ga = A.ga * B.al + A.de * B.ga;
    r.de = A.ga * B.be + A.de * B.de;
    r.c  = A.c * B.c;
    r.e  = A.e * B.al + A.c * B.e + A.f * B.ga;
    r.f  = A.e * B.be + A.c * B.f + A.f * B.de;
    return r;
}

// Scale-invariant normalization; guarded so it can never manufacture NaN/Inf.
// Inputs to every unnormalized scan segment are normalized (max entry <= 1),
// so growth over <=6 unnormalized compose rounds is bounded (<~1e19) — far
// inside fp64 range; we normalize only at segment boundaries.
__device__ __forceinline__ void dmat_normalize(DMat& m) {
    double mx = fmax(fabs(m.al), fabs(m.be));
    mx = fmax(mx, fabs(m.ga));
    mx = fmax(mx, fabs(m.de));
    mx = fmax(mx, fabs(m.c));
    mx = fmax(mx, fabs(m.e));
    mx = fmax(mx, fabs(m.f));
    if (!(mx > 0.0) || isinf(mx)) return;   // all-zero or corrupt: leave as-is
    double inv = 1.0 / mx;
    m.al *= inv; m.be *= inv; m.ga *= inv; m.de *= inv;
    m.c *= inv; m.e *= inv; m.f *= inv;
}

__device__ __forceinline__ DMat dmat_shfl_up(const DMat& m, int d) {
    DMat r;
    r.al = __shfl_up(m.al, d); r.be = __shfl_up(m.be, d);
    r.ga = __shfl_up(m.ga, d); r.de = __shfl_up(m.de, d);
    r.c  = __shfl_up(m.c,  d); r.e  = __shfl_up(m.e,  d);
    r.f  = __shfl_up(m.f,  d);
    return r;
}

__device__ __forceinline__ DMat dmat_shfl_bcast(const DMat& m, int src) {
    DMat r;
    r.al = __shfl(m.al, src); r.be = __shfl(m.be, src);
    r.ga = __shfl(m.ga, src); r.de = __shfl(m.de, src);
    r.c  = __shfl(m.c,  src); r.e  = __shfl(m.e,  src);
    r.f  = __shfl(m.f,  src);
    return r;
}

// Barrier-free inclusive scan across the 64 lanes of a wave.
__device__ __forceinline__ DMat dmat_wave_scan64(DMat mine, int lane) {
    #pragma unroll
    for (int d = 1; d < 64; d <<= 1) {
        DMat o = dmat_shfl_up(mine, d);
        if (lane >= d) mine = dmat_compose(mine, o);
    }
    return mine;
}

__device__ __forceinline__ DMat elem_mat(double P, double a, double U, double V, double yy) {
    double p = P * P;
    DMat m;
    m.al = p * (a - 2.0 * U * V);
    m.be = V * V;
    m.ga = -(p * U * U);
    m.de = a;
    m.c  = P * (a - U * V);
    m.e  = -(yy * p * U);
    m.f  = yy * V;
    return m;
}

// Register-resident 4-way select (avoid runtime-indexed array -> scratch).
__device__ __forceinline__ double band_amp(int b, double a1, double a2, double a3) {
    double lo = (b & 1) ? a1 : 1.0;
    double hi = (b & 1) ? a3 : a2;
    return (b & 2) ? hi : lo;
}

// Device-coherent (agent-scope) matrix store/load for cross-block handoff.
__device__ __forceinline__ void dmat_store_agent(double* p, const DMat& m) {
    __hip_atomic_store(&p[0], m.al, __ATOMIC_RELAXED, __HIP_MEMORY_SCOPE_AGENT);
    __hip_atomic_store(&p[1], m.be, __ATOMIC_RELAXED, __HIP_MEMORY_SCOPE_AGENT);
    __hip_atomic_store(&p[2], m.ga, __ATOMIC_RELAXED, __HIP_MEMORY_SCOPE_AGENT);
    __hip_atomic_store(&p[3], m.de, __ATOMIC_RELAXED, __HIP_MEMORY_SCOPE_AGENT);
    __hip_atomic_store(&p[4], m.c,  __ATOMIC_RELAXED, __HIP_MEMORY_SCOPE_AGENT);
    __hip_atomic_store(&p[5], m.e,  __ATOMIC_RELAXED, __HIP_MEMORY_SCOPE_AGENT);
    __hip_atomic_store(&p[6], m.f,  __ATOMIC_RELAXED, __HIP_MEMORY_SCOPE_AGENT);
}

__device__ __forceinline__ DMat dmat_load_agent(const double* p) {
    DMat m;
    m.al = __hip_atomic_load(&p[0], __ATOMIC_RELAXED, __HIP_MEMORY_SCOPE_AGENT);
    m.be = __hip_atomic_load(&p[1], __ATOMIC_RELAXED, __HIP_MEMORY_SCOPE_AGENT);
    m.ga = __hip_atomic_load(&p[2], __ATOMIC_RELAXED, __HIP_MEMORY_SCOPE_AGENT);
    m.de = __hip_atomic_load(&p[3], __ATOMIC_RELAXED, __HIP_MEMORY_SCOPE_AGENT);
    m.c  = __hip_atomic_load(&p[4], __ATOMIC_RELAXED, __HIP_MEMORY_SCOPE_AGENT);
    m.e  = __hip_atomic_load(&p[5], __ATOMIC_RELAXED, __HIP_MEMORY_SCOPE_AGENT);
    m.f  = __hip_atomic_load(&p[6], __ATOMIC_RELAXED, __HIP_MEMORY_SCOPE_AGENT);
    return m;
}

// ------------------------- single fused kernel ---------------------------
// NT=512 so the allocator has a 256-VGPR budget (launch_bounds min 2
// waves/EU) — the ~150-200 VGPR demand CANNOT spill (rounds 3/4 lesson:
// 1024-thread blocks pin 64 VGPRs and spill 20+ MB).
// phase 1: per-thread chain (replay data register-resident, 49 VGPR) +
//          barrier-free shuffle wave scan + 1 LDS step for 8 wave totals
// grid barrier (256 blocks = 1 block/CU -> always co-resident)
// phase 2: redundant spine shuffle-scan of 256 block composites (4 waves)
// phase 3: replay from registers, reduce, done-counter finalize
__global__ __launch_bounds__(NT, 2) void k_fused(    // 2 waves/EU -> 256 VGPR cap
    const float* __restrict__ t, const int* __restrict__ band,
    const float* __restrict__ y, const float* __restrict__ yerr,
    const float* __restrict__ lad, const float* __restrict__ lkp,
    double* __restrict__ L, double* __restrict__ accum,
    unsigned int* __restrict__ bar0, unsigned int* __restrict__ done,
    float* __restrict__ out)
{
    __shared__ double totW[7 * NWAVE];   // 8 wave totals
    __shared__ double spI[7 * NB];       // 256 spine inclusive values
    __shared__ double spT[7 * 4];        // 4 spine wave totals
    __shared__ double red[2 * NWAVE];

    const int tid  = threadIdx.x;
    const int lane = tid & 63;
    const int wid  = tid >> 6;
    const int bid  = blockIdx.x;

    const double sigma2 = exp(2.0 * (double)lkp[0]);
    const float inv_ell_f = expf(-lkp[1]);
    const double amp1 = exp((double)lad[0]);
    const double amp2 = exp((double)lad[1]);
    const double amp3 = exp((double)lad[2]);

    const int gid  = bid * NT + tid;
    const int base = gid * NC;
    const bool first = (gid == 0);

    float tpA = first ? 0.0f : t[base - 1];
    float tpB = t[base + NC / 2 - 1];

    // replay state: 3x16 fp32 + 1 packed-band u32 = 49 VGPRs
    float Pv[NC], av[NC], yvv[NC];
    unsigned int bpack = 0;

    // ---- phase 1: two independent 8-element chains (2x ILP) ----
    DMat accA = dmat_identity();
    DMat accB = dmat_identity();
    #pragma unroll
    for (int kk = 0; kk < NC / 2; kk += 4) {
        float4 tvA = *reinterpret_cast<const float4*>(t + base + kk);
        float4 yvA = *reinterpret_cast<const float4*>(y + base + kk);
        float4 evA = *reinterpret_cast<const float4*>(yerr + base + kk);
        int4   bvA = *reinterpret_cast<const int4*>(band + base + kk);
        float4 tvB = *reinterpret_cast<const float4*>(t + base + NC / 2 + kk);
        float4 yvB = *reinterpret_cast<const float4*>(y + base + NC / 2 + kk);
        float4 evB = *reinterpret_cast<const float4*>(yerr + base + NC / 2 + kk);
        int4   bvB = *reinterpret_cast<const int4*>(band + base + NC / 2 + kk);
        float tA[4] = {tvA.x, tvA.y, tvA.z, tvA.w};
        float yA[4] = {yvA.x, yvA.y, yvA.z, yvA.w};
        float eA[4] = {evA.x, evA.y, evA.z, evA.w};
        int   bA[4] = {bvA.x, bvA.y, bvA.z, bvA.w};
        float tB[4] = {tvB.x, tvB.y, tvB.z, tvB.w};
        float yB[4] = {yvB.x, yvB.y, yvB.z, yvB.w};
        float eB[4] = {evB.x, evB.y, evB.z, evB.w};
        int   bB[4] = {bvB.x, bvB.y, bvB.z, bvB.w};
        #pragma unroll
        for (int j = 0; j < 4; ++j) {
            {   // chain A: elements [0, 8)
                int b = bA[j] & 3;
                bpack |= (unsigned int)b << (2 * (kk + j));
                double u = band_amp(b, amp1, amp2, amp3);
                double U = sigma2 * u;
                double a = (double)eA[j] * (double)eA[j] + U * u;
                float dt = tA[j] - tpA; tpA = tA[j];
                float pf = (first && kk == 0 && j == 0)
                         ? 0.0f : expf(-dt * inv_ell_f);
                Pv[kk + j] = pf; av[kk + j] = (float)a; yvv[kk + j] = yA[j];
                accA = dmat_compose(elem_mat((double)pf, a, U, u, (double)yA[j]), accA);
            }
            {   // chain B: elements [8, 16) — independent of chain A
                int ix = NC / 2 + kk + j;
                int b = bB[j] & 3;
                bpack |= (unsigned int)b << (2 * ix);
                double u = band_amp(b, amp1, amp2, amp3);
                double U = sigma2 * u;
                double a = (double)eB[j] * (double)eB[j] + U * u;
                float dt = tB[j] - tpB; tpB = tB[j];
                float pf = expf(-dt * inv_ell_f);
                Pv[ix] = pf; av[ix] = (float)a; yvv[ix] = yB[j];
                accB = dmat_compose(elem_mat((double)pf, a, U, u, (double)yB[j]), accB);
            }
        }
    }
    DMat acc = dmat_compose(accB, accA);
    dmat_normalize(acc);

    // ---- barrier-free wave scan; 1 LDS step for the 8 wave totals ----
    DMat incl = dmat_wave_scan64(acc, lane);
    dmat_normalize(incl);
    DMat laneExcl = dmat_shfl_up(incl, 1);   // lane 0: garbage (handled below)
    if (lane == 63) {                        // publish wave total
        totW[0 * NWAVE + wid] = incl.al; totW[1 * NWAVE + wid] = incl.be;
        totW[2 * NWAVE + wid] = incl.ga; totW[3 * NWAVE + wid] = incl.de;
        totW[4 * NWAVE + wid] = incl.c;  totW[5 * NWAVE + wid] = incl.e;
        totW[6 * NWAVE + wid] = incl.f;
    }
    __syncthreads();

    // redundant 8-element shuffle scan of wave totals (every wave; no barrier)
    DMat tv = dmat_identity();
    if (lane < NWAVE) {
        tv.al = totW[0 * NWAVE + lane]; tv.be = totW[1 * NWAVE + lane];
        tv.ga = totW[2 * NWAVE + lane]; tv.de = totW[3 * NWAVE + lane];
        tv.c  = totW[4 * NWAVE + lane]; tv.e  = totW[5 * NWAVE + lane];
        tv.f  = totW[6 * NWAVE + lane];
    }
    #pragma unroll
    for (int d = 1; d < NWAVE; d <<= 1) {
        DMat o = dmat_shfl_up(tv, d);
        if (lane >= d && lane < NWAVE) tv = dmat_compose(tv, o);
    }
    dmat_normalize(tv);

    // publish block-inclusive composite (scanned[7] lives in lane 7, wave 0)
    if (tid == NWAVE - 1) {
        dmat_store_agent(L + bid * 7, tv);
        __threadfence();                     // release: L visible device-wide
    }

    // wave-exclusive prefix within block; thread-exclusive within block
    DMat Et;
    if (wid == 0) {
        Et = (lane == 0) ? dmat_identity() : laneExcl;
    } else {
        DMat waveExcl = dmat_shfl_bcast(tv, wid - 1);
        Et = (lane == 0) ? waveExcl : dmat_compose(laneExcl, waveExcl);
    }

    // ---- grid barrier ----
    __syncthreads();
    if (tid == 0) {
        __threadfence();
        atomicAdd(bar0, 1u);
        while (__hip_atomic_load(bar0, __ATOMIC_ACQUIRE,
                                 __HIP_MEMORY_SCOPE_AGENT) < NB) {
            __builtin_amdgcn_s_sleep(2);
        }
    }
    __syncthreads();

    // ---- phase 2: redundant spine scan (4 waves shuffle-scan 256 blocks) ----
    if (wid < 4) {
        DMat sv = dmat_load_agent(L + tid * 7);   // tid < 256 here
        sv = dmat_wave_scan64(sv, lane);
        dmat_normalize(sv);
        spI[0 * NB + tid] = sv.al; spI[1 * NB + tid] = sv.be;
        spI[2 * NB + tid] = sv.ga; spI[3 * NB + tid] = sv.de;
        spI[4 * NB + tid] = sv.c;  spI[5 * NB + tid] = sv.e;
        spI[6 * NB + tid] = sv.f;
        if (lane == 63) {
            spT[0 * 4 + wid] = sv.al; spT[1 * 4 + wid] = sv.be;
            spT[2 * 4 + wid] = sv.ga; spT[3 * 4 + wid] = sv.de;
            spT[4 * 4 + wid] = sv.c;  spT[5 * 4 + wid] = sv.e;
            spT[6 * 4 + wid] = sv.f;
        }
    }
    __syncthreads();

    // block-exclusive composite Eb (uniform; LDS broadcast reads)
    DMat Eb = dmat_identity();
    if (bid > 0) {
        const int i = bid - 1;
        Eb.al = spI[0 * NB + i]; Eb.be = spI[1 * NB + i];
        Eb.ga = spI[2 * NB + i]; Eb.de = spI[3 * NB + i];
        Eb.c  = spI[4 * NB + i]; Eb.e  = spI[5 * NB + i];
        Eb.f  = spI[6 * NB + i];
        const int nw = i >> 6;
        for (int w = nw - 1; w >= 0; --w) {
            DMat T;
            T.al = spT[0 * 4 + w]; T.be = spT[1 * 4 + w];
            T.ga = spT[2 * 4 + w]; T.de = spT[3 * 4 + w];
            T.c  = spT[4 * 4 + w]; T.e  = spT[5 * 4 + w];
            T.f  = spT[6 * 4 + w];
            Eb = dmat_compose(Eb, T);
        }
        dmat_normalize(Eb);
    }

    // full-history exclusive composite for this thread
    DMat F = dmat_compose(Et, Eb);
    dmat_normalize(F);
    // apply at (x,g) = (0,0); x=0 is far from the repelling fixed point (~1)
    double x = 0.0, g = 0.0;
    if (F.de != 0.0 && !isinf(F.de)) {
        double invde = 1.0 / F.de;
        x = F.be * invde;
        g = F.f  * invde;
    }
    if (!isfinite(x)) x = 0.0;
    if (!isfinite(g)) g = 0.0;

    // ---- phase 3: replay from registers (u,U,V recomputed from bpack) ----
    double s_logD = 0.0, s_quad = 0.0, pd = 1.0;
    #pragma unroll
    for (int k = 0; k < NC; ++k) {
        int b = (int)((bpack >> (2 * k)) & 3u);
        double V = band_amp(b, amp1, amp2, amp3);
        double U = sigma2 * V;
        double P = (double)Pv[k], a = (double)av[k], yy = (double)yvv[k];
        double p = P * P;
        double S = p * x;
        double D = a - U * U * S;
        if (!(D > 1e-300)) D = 1e-300;  // NaN-proof; never triggers if math is right
        double invD = 1.0 / D;
        double W = (V - S * U) * invD;
        double gn = P * g;
        double z = yy - U * gn;
        pd *= D;
        s_quad = fma(z * z, invD, s_quad);
        x = fma(D * W, W, S);
        g = fma(W, z, gn);
        if ((k & 7) == 7) {            // fold product every 8 elements
            s_logD += log(pd);
            pd = 1.0;
        }
    }

    // wave reduce, then cross-wave step
    #pragma unroll
    for (int off = 32; off > 0; off >>= 1) {
        s_logD += __shfl_down(s_logD, off);
        s_quad += __shfl_down(s_quad, off);
    }
    if (lane == 0) { red[wid] = s_logD; red[NWAVE + wid] = s_quad; }
    __syncthreads();
    if (tid == 0) {
        double l = 0.0, q = 0.0;
        #pragma unroll
        for (int w = 0; w < NWAVE; ++w) { l += red[w]; q += red[NWAVE + w]; }
        atomicAdd(&accum[0], l);
        atomicAdd(&accum[1], q);
        __threadfence();
        unsigned int old = atomicAdd(done, 1u);
        if (old == NB - 1) {   // last block: finalize (atomic RMW reads = coherent)
            double LL = atomicAdd(&accum[0], 0.0);
            double QQ = atomicAdd(&accum[1], 0.0);
            out[0] = (float)(-0.5 * (QQ + LL
                     + (double)N_TOTAL * 1.8378770664093454836));  // log(2*pi)
        }
    }
}

extern "C" void kernel_launch(void* const* d_in, const int* in_sizes, int n_in,
                              void* d_out, int out_size, void* d_ws, size_t ws_size,
                              hipStream_t stream)
{
    const float* t    = (const float*)d_in[0];
    const int*   band = (const int*)d_in[1];
    const float* y    = (const float*)d_in[2];
    const float* yerr = (const float*)d_in[3];
    const float* lad  = (const float*)d_in[4];
    const float* lkp  = (const float*)d_in[5];

    double* dws        = (double*)d_ws;
    double* accum      = dws;                         // 2 doubles
    unsigned int* ctrs = (unsigned int*)(dws + 2);    // bar0, done
    double* L          = dws + 4;                     // NB * 7 doubles (14 KB)

    // zero accum + control words (workspace is poisoned between iterations)
    hipMemsetAsync(dws, 0, 32, stream);
    k_fused<<<NB, NT, 0, stream>>>(t, band, y, yerr, lad, lkp,
                                   L, accum, ctrs, ctrs + 1, (float*)d_out);
}